// Round 12
// baseline (1310.890 us; speedup 1.0000x reference)
//
#include <hip/hip_runtime.h>
#include <math.h>

#define DEV static __device__ __forceinline__

typedef __attribute__((ext_vector_type(4))) float f32x4;
typedef __attribute__((ext_vector_type(16))) float f32x16;
typedef __attribute__((ext_vector_type(2))) float f32x2;
typedef __attribute__((ext_vector_type(8))) short bf16x8;

#define B_    2048
#define N_    100000
#define E_    512
#define KTOP  16
#define CHUNK 3125
#define NCHUNK 32
#define KVR   32                       /* corpus rows per jt tile */
#define SLAB  528                      /* 33*16B granule stride */
#define TOPS  6                        /* top-6 per (chunk, lane-hi stripe) */
#define NCAND (NCHUNK*2*TOPS)          /* 384 per row */
#define NSEL  48
#define NEGINF (-__builtin_inff())

DEV unsigned short f2bf(float f){
  union { float f; unsigned u; } v; v.f = f;
  unsigned r = v.u + 0x7fffu + ((v.u >> 16) & 1u);
  return (unsigned short)(r >> 16);
}

DEV f32x16 mfma32(bf16x8 a, bf16x8 b, f32x16 c){
  return __builtin_amdgcn_mfma_f32_32x32x16_bf16(a, b, c, 0, 0, 0);
}
DEV f32x4 mfma16(bf16x8 a, bf16x8 b, f32x4 c){
  return __builtin_amdgcn_mfma_f32_16x16x32_bf16(a, b, c, 0, 0, 0);
}
DEV f32x16 zero16(){
  f32x16 z;
  #pragma unroll
  for (int i = 0; i < 16; i++) z[i] = 0.f;
  return z;
}

// swizzled LDS helpers for bf16 tiles (byte ^= (row&7)<<4) — used by k_gemm_bf16
DEV void lds_w8(unsigned short* base, int row, int k, int stride, bf16x8 v){
  char* p = (char*)base + (((row*stride + k)*2) ^ ((row & 7) << 4));
  *(bf16x8*)p = v;
}
DEV bf16x8 lds_r8(const unsigned short* base, int row, int k, int stride){
  const char* p = (const char*)base + (((row*stride + k)*2) ^ ((row & 7) << 4));
  return *(const bf16x8*)p;
}

// ---------------- fused row L2-normalize + bf16 convert (1 wave / row) -------
__global__ void k_norm_bf16(const float* __restrict__ x, unsigned short* __restrict__ out, int rows){
  int gw = (blockIdx.x * 256 + threadIdx.x) >> 6;
  int lane = threadIdx.x & 63;
  if (gw >= rows) return;
  const float* r = x + (long)gw * E_;
  f32x4 v0 = *(const f32x4*)(r + lane*8);
  f32x4 v1 = *(const f32x4*)(r + lane*8 + 4);
  float s = v0[0]*v0[0]+v0[1]*v0[1]+v0[2]*v0[2]+v0[3]*v0[3]
          + v1[0]*v1[0]+v1[1]*v1[1]+v1[2]*v1[2]+v1[3]*v1[3];
  #pragma unroll
  for (int o = 32; o; o >>= 1) s += __shfl_xor(s, o, 64);
  float inv = 1.f / fmaxf(sqrtf(s), 1e-12f);
  bf16x8 o;
  o[0]=(short)f2bf(v0[0]*inv); o[1]=(short)f2bf(v0[1]*inv); o[2]=(short)f2bf(v0[2]*inv); o[3]=(short)f2bf(v0[3]*inv);
  o[4]=(short)f2bf(v1[0]*inv); o[5]=(short)f2bf(v1[1]*inv); o[6]=(short)f2bf(v1[2]*inv); o[7]=(short)f2bf(v1[3]*inv);
  *(bf16x8*)(out + (long)gw*E_ + lane*8) = o;
}

// ---------------- fp32 GEMM (encoders): C = act(A @ W + b), W is [K,N] ------
// Scalar-B wave-strip SGEMM (R11 lesson: the LDS-tiled 64x64/4x4 version is
// pinned at the 52TF LDS-pipe ceiling — 2 B/FMA). Here each wave owns a
// 64-row x 8-col strip: B[k][n0..n7] is WAVE-UNIFORM -> scalar s_load path
// (SMEM pipe, free); A is 1 ds_read_b32/lane/k (bank (4k+lane)%32 = 2-way,
// free). LDS bytes/FMA = 0.5 -> VALU-bound. Tile 64x32, 256 thr, grid ~1024
// = 4 blocks/CU = 16 waves/CU, VGPR ~30.
template<int NSEG, bool RELU>
__global__ __launch_bounds__(256) void k_gemm_f32(
    const float* __restrict__ A0, int K0,
    const float* __restrict__ A1, int K1,
    const float* __restrict__ Bw, const float* __restrict__ bias,
    float* __restrict__ C, int N, int Ktot)
{
  __shared__ float At[2][16][68];   // [buf][k][m]
  int bm = blockIdx.x * 64, bn = blockIdx.y * 32;
  int t = threadIdx.x, lane = t & 63;
  int ws8 = __builtin_amdgcn_readfirstlane(((t >> 6) << 3));  // wave n-offset
  int srow = t & 63, skq = (t >> 6) << 2;   // stage: row, 4-k group
  float acc[8] = {};

  // stage k0=0 into buf 0
  {
    const float* src = A0; int kk = skq, ld = K0;
    if (NSEG == 2 && skq >= K0){ src = A1; kk = skq - K0; ld = K1; }
    f32x4 v = *(const f32x4*)(src + (long)(bm + srow) * ld + kk);
    #pragma unroll
    for (int i = 0; i < 4; i++) At[0][skq + i][srow] = v[i];
  }
  __syncthreads();

  for (int k0 = 0; k0 < Ktot; k0 += 16){
    int cur = (k0 >> 4) & 1;
    // stage next k-tile into the other buffer (no extra barrier: write buf^1)
    if (k0 + 16 < Ktot){
      int gk = k0 + 16 + skq;
      const float* src = A0; int kk = gk, ld = K0;
      if (NSEG == 2 && gk >= K0){ src = A1; kk = gk - K0; ld = K1; }
      f32x4 v = *(const f32x4*)(src + (long)(bm + srow) * ld + kk);
      #pragma unroll
      for (int i = 0; i < 4; i++) At[cur ^ 1][gk - k0 - 16 + i][srow] = v[i];
    }
    const float* brow = Bw + (long)k0 * N + bn + ws8;
    #pragma unroll
    for (int k = 0; k < 16; k++){
      float a = At[cur][k][lane];
      const float* bp = brow + (long)k * N;   // wave-uniform -> s_load
      #pragma unroll
      for (int j = 0; j < 8; j++) acc[j] += a * bp[j];
    }
    __syncthreads();
  }

  const float* bp = bias + bn + ws8;
  #pragma unroll
  for (int j = 0; j < 8; j++){
    float x = acc[j] + bp[j];
    C[(long)(bm + lane) * N + bn + ws8 + j] = RELU ? fmaxf(x, 0.f) : x;
  }
}

// ---------------- transpose fp32 [K,N] -> bf16 [N,K] ----------------
__global__ void k_transpose_bf16(const float* __restrict__ W, unsigned short* __restrict__ WT, int K, int N){
  __shared__ float tile[32][33];
  int k0 = blockIdx.x * 32, n0 = blockIdx.y * 32;
  int tx = threadIdx.x & 31, ty = threadIdx.x >> 5;
  #pragma unroll
  for (int r = 0; r < 32; r += 8) tile[ty + r][tx] = W[(long)(k0 + ty + r) * N + n0 + tx];
  __syncthreads();
  #pragma unroll
  for (int r = 0; r < 32; r += 8) WT[(long)(n0 + ty + r) * K + k0 + tx] = f2bf(tile[tx][ty + r]);
}

// ---------------- bf16 MFMA NT GEMM: C = act(A @ Bt^T + bias) ----------------
template<int NSEG, bool AF32, bool RELU, bool OUTBF16>
__global__ __launch_bounds__(256) void k_gemm_bf16(
    const void* __restrict__ A0p, int K0,
    const void* __restrict__ A1p, int K1,
    const void* __restrict__ A2p,
    const unsigned short* __restrict__ Bt, const float* __restrict__ bias,
    void* __restrict__ Cp, int N, int Ktot)
{
  __shared__ unsigned short Ash[64*64];
  __shared__ unsigned short Bsh[64*64];
  int bm = blockIdx.x * 64, bn = blockIdx.y * 64;
  int t = threadIdx.x, lane = t & 63, wid = t >> 6;
  int wr = wid >> 1, wc = wid & 1;
  int r16 = lane & 15, khalf = lane >> 4;
  int srow = t >> 2, skc = (t & 3) * 16;
  f32x4 acc00 = {0,0,0,0}, acc01 = {0,0,0,0}, acc10 = {0,0,0,0}, acc11 = {0,0,0,0};

  for (int k0 = 0; k0 < Ktot; k0 += 64){
    int gk = k0 + skc;
    if (!AF32){
      const unsigned short* A = (const unsigned short*)A0p;
      const unsigned short* s = A + (long)(bm + srow) * Ktot + gk;
      lds_w8(Ash, srow, skc,     64, *(const bf16x8*)s);
      lds_w8(Ash, srow, skc + 8, 64, *(const bf16x8*)(s + 8));
    } else {
      const float* s; int kk, ld;
      if (NSEG >= 2 && gk >= K0){
        if (NSEG == 3 && gk >= K0 + K1){ s = (const float*)A2p; kk = gk - K0 - K1; ld = Ktot - K0 - K1; }
        else                           { s = (const float*)A1p; kk = gk - K0;      ld = K1; }
      } else { s = (const float*)A0p; kk = gk; ld = K0; }
      const float* p = s + (long)(bm + srow) * ld + kk;
      f32x4 f0 = *(const f32x4*)p, f1 = *(const f32x4*)(p+4), f2 = *(const f32x4*)(p+8), f3 = *(const f32x4*)(p+12);
      bf16x8 v0, v1;
      v0[0]=(short)f2bf(f0[0]); v0[1]=(short)f2bf(f0[1]); v0[2]=(short)f2bf(f0[2]); v0[3]=(short)f2bf(f0[3]);
      v0[4]=(short)f2bf(f1[0]); v0[5]=(short)f2bf(f1[1]); v0[6]=(short)f2bf(f1[2]); v0[7]=(short)f2bf(f1[3]);
      v1[0]=(short)f2bf(f2[0]); v1[1]=(short)f2bf(f2[1]); v1[2]=(short)f2bf(f2[2]); v1[3]=(short)f2bf(f2[3]);
      v1[4]=(short)f2bf(f3[0]); v1[5]=(short)f2bf(f3[1]); v1[6]=(short)f2bf(f3[2]); v1[7]=(short)f2bf(f3[3]);
      lds_w8(Ash, srow, skc, 64, v0);
      lds_w8(Ash, srow, skc + 8, 64, v1);
    }
    const unsigned short* bs = Bt + (long)(bn + srow) * Ktot + gk;
    lds_w8(Bsh, srow, skc,     64, *(const bf16x8*)bs);
    lds_w8(Bsh, srow, skc + 8, 64, *(const bf16x8*)(bs + 8));
    __syncthreads();
    #pragma unroll
    for (int ks = 0; ks < 2; ks++){
      int kb = ks*32 + khalf*8;
      bf16x8 a0 = lds_r8(Ash, wr*32 +      r16, kb, 64);
      bf16x8 a1 = lds_r8(Ash, wr*32 + 16 + r16, kb, 64);
      bf16x8 b0 = lds_r8(Bsh, wc*32 +      r16, kb, 64);
      bf16x8 b1 = lds_r8(Bsh, wc*32 + 16 + r16, kb, 64);
      acc00 = mfma16(a0, b0, acc00);
      acc01 = mfma16(a0, b1, acc01);
      acc10 = mfma16(a1, b0, acc10);
      acc11 = mfma16(a1, b1, acc11);
    }
    __syncthreads();
  }
  #pragma unroll
  for (int r = 0; r < 4; r++){
    int mA = bm + wr*32 +      khalf*4 + r;
    int mB = bm + wr*32 + 16 + khalf*4 + r;
    int nA = bn + wc*32 +      r16;
    int nB = bn + wc*32 + 16 + r16;
    float v00 = acc00[r] + bias[nA]; float v01 = acc01[r] + bias[nB];
    float v10 = acc10[r] + bias[nA]; float v11 = acc11[r] + bias[nB];
    if (RELU){ v00 = fmaxf(v00,0.f); v01 = fmaxf(v01,0.f); v10 = fmaxf(v10,0.f); v11 = fmaxf(v11,0.f); }
    if (OUTBF16){
      unsigned short* C = (unsigned short*)Cp;
      C[(long)mA*N + nA] = f2bf(v00); C[(long)mA*N + nB] = f2bf(v01);
      C[(long)mB*N + nA] = f2bf(v10); C[(long)mB*N + nB] = f2bf(v11);
    } else {
      float* C = (float*)Cp;
      C[(long)mA*N + nA] = v00; C[(long)mA*N + nB] = v01;
      C[(long)mB*N + nA] = v10; C[(long)mB*N + nB] = v11;
    }
  }
}

// ---------------- similarity GEMM + fused in-register top-6 ------------------
// (unchanged from R11: 306us, SQ_LDS_BANK_CONFLICT = 0)
__global__ __launch_bounds__(512) __attribute__((amdgpu_waves_per_eu(2, 2)))
void k_sim_topk(
    const unsigned short* __restrict__ Qb, const unsigned short* __restrict__ Cb,
    float* __restrict__ candS, int* __restrict__ candI)
{
  __shared__ char Csh0[64*SLAB];   // 33 KB
  __shared__ char Csh1[64*SLAB];   // 33 KB
  int bid = blockIdx.x;
  int chunk = ((bid & 7) << 2) | (bid >> 6);
  int rowtile = (bid >> 3) & 7;
  int t = threadIdx.x, lane = t & 63, wid = t >> 6;   // wid 0..7
  int q32 = lane & 31, hi = lane >> 5;
  int jb0 = chunk * CHUNK;
  const int njt = (CHUNK + KVR - 1) / KVR;            // 98 (even)

  bf16x8 qreg[32];
  {
    const unsigned short* qb = Qb + ((long)(rowtile*256 + wid*32 + q32) << 9) + hi*8;
    #pragma unroll
    for (int ks = 0; ks < 32; ks++)
      qreg[ks] = *(const bf16x8*)(qb + ks*16);
  }
  #pragma unroll
  for (int ks = 0; ks < 32; ks++)
    asm volatile("" : "+v"(qreg[ks]));

  float ts[TOPS]; int ti[TOPS];
  #pragma unroll
  for (int q = 0; q < TOPS; q++){ ts[q] = NEGINF; ti[q] = 0; }
  float rmn = NEGINF;

  int lr = t >> 4;                                    // 0..31
  const char* gsrc = (const char*)Cb + (long)(jb0 + lr) * 1024 + (t & 15) * 16;
  unsigned wbase = (unsigned)((t & 15) * SLAB + lr * 16);
  unsigned rbase = (unsigned)(hi * SLAB + q32 * 16);

  auto dosel = [&](f32x16 a, int jb, int nv, bool tail){
    if (tail){
      #pragma unroll
      for (int r = 0; r < 16; r++){
        int crow = (r & 3) + 8*(r >> 2) + 4*hi;
        if (crow >= nv) a[r] = NEGINF;
      }
    }
    float m16 = a[0];
    #pragma unroll
    for (int r = 1; r < 16; r++) m16 = fmaxf(m16, a[r]);
    if (m16 > rmn){
      #pragma unroll
      for (int r = 0; r < 16; r++){
        float s = a[r];
        if (s > rmn){
          int j = jb + (r & 3) + 8*(r >> 2) + 4*hi;
          float mn = ts[0]; int ms = 0;
          #pragma unroll
          for (int q = 1; q < TOPS; q++){ bool lt = ts[q] < mn; mn = lt ? ts[q] : mn; ms = lt ? q : ms; }
          #pragma unroll
          for (int q = 0; q < TOPS; q++){ bool h = (ms == q); ts[q] = h ? s : ts[q]; ti[q] = h ? j : ti[q]; }
          float nm = ts[0];
          #pragma unroll
          for (int q = 1; q < TOPS; q++) nm = fminf(nm, ts[q]);
          rmn = nm;
        }
      }
    }
  };

  auto step = [&](int jt, const char* rbuf, char* wbuf){
    bool haveNext = (jt + 1 < njt);
    f32x4 n0, n1, n2, n3;
    if (haveNext){
      n0 = *(const f32x4*)(gsrc);
      n1 = *(const f32x4*)(gsrc + 256);
      n2 = *(const f32x4*)(gsrc + 512);
      n3 = *(const f32x4*)(gsrc + 768);
      gsrc += KVR * 1024;
    }
    f32x16 accA = zero16(), accB = zero16();
    const char* rp = rbuf + rbase;
    #pragma unroll
    for (int ks = 0; ks < 32; ks += 2){
      bf16x8 a0 = *(const bf16x8*)(rp + ks*(2*SLAB));
      bf16x8 a1 = *(const bf16x8*)(rp + (ks+1)*(2*SLAB));
      accA = mfma32(a0, qreg[ks],   accA);
      accB = mfma32(a1, qreg[ks+1], accB);
    }
    f32x16 acc = accA + accB;
    if (haveNext){
      char* wb = wbuf + wbase;
      *(f32x4*)(wb)            = n0;
      *(f32x4*)(wb + 16*SLAB)  = n1;
      *(f32x4*)(wb + 32*SLAB)  = n2;
      *(f32x4*)(wb + 48*SLAB)  = n3;
    }
    int jb = jb0 + jt*KVR;
    int nv = jb0 + CHUNK - jb;
    dosel(acc, jb, nv, nv < KVR);
    __syncthreads();
  };

  {
    f32x4 s0 = *(const f32x4*)(gsrc);
    f32x4 s1 = *(const f32x4*)(gsrc + 256);
    f32x4 s2 = *(const f32x4*)(gsrc + 512);
    f32x4 s3 = *(const f32x4*)(gsrc + 768);
    gsrc += KVR * 1024;
    char* wb = Csh0 + wbase;
    *(f32x4*)(wb)            = s0;
    *(f32x4*)(wb + 16*SLAB)  = s1;
    *(f32x4*)(wb + 32*SLAB)  = s2;
    *(f32x4*)(wb + 48*SLAB)  = s3;
    __syncthreads();
  }
  for (int jt = 0; jt < njt; jt += 2){
    step(jt,     Csh0, Csh1);
    step(jt + 1, Csh1, Csh0);
  }

  {
    int grow = rowtile*256 + wid*32 + q32;
    long o = (((long)grow * NCHUNK + chunk) * 2 + hi) * TOPS;
    #pragma unroll
    for (int q = 0; q < TOPS; q++){ candS[o+q] = ts[q]; candI[o+q] = ti[q]; }
  }
}

// ---------------- finalize: wave-per-row, register merge + fp64 rescore ------
__global__ __launch_bounds__(256) void k_finalize(
    const float* __restrict__ candS, const int* __restrict__ candI,
    const float* __restrict__ contrast, const float* __restrict__ corpus,
    float* __restrict__ outScore, float* __restrict__ outIdxF, int* __restrict__ outIdxI)
{
  int t = threadIdx.x, lane = t & 63, wid = t >> 6;
  int row = blockIdx.x * 4 + wid;

  float cs[6]; int ci[6];
  {
    const float* cp = candS + (long)row * NCAND + lane * 6;
    const int*   ip = candI + (long)row * NCAND + lane * 6;
    #pragma unroll
    for (int c = 0; c < 6; c++){ cs[c] = cp[c]; ci[c] = ip[c]; }
  }
  f32x4 q0 = *(const f32x4*)(contrast + (long)row*E_ + lane*8);
  f32x4 q1 = *(const f32x4*)(contrast + (long)row*E_ + lane*8 + 4);
  double qs = 0.0;
  #pragma unroll
  for (int u = 0; u < 4; u++){ qs += (double)q0[u]*(double)q0[u]; qs += (double)q1[u]*(double)q1[u]; }
  #pragma unroll
  for (int o = 32; o; o >>= 1) qs += __shfl_xor(qs, o, 64);
  double qn = fmax(sqrt(qs), 1e-12);

  float cm = cs[0]; int cpos = 0, cj = ci[0];
  #pragma unroll
  for (int c = 1; c < 6; c++){ bool g = cs[c] > cm; cm = g ? cs[c] : cm; cpos = g ? c : cpos; cj = g ? ci[c] : cj; }

  int selj = 0;
  for (int r = 0; r < NSEL; r++){
    float bs = cm; int bj = cj; int bl = lane;
    #pragma unroll
    for (int o = 32; o; o >>= 1){
      float os = __shfl_xor(bs, o, 64);
      int   oj = __shfl_xor(bj, o, 64);
      int   ol = __shfl_xor(bl, o, 64);
      bool take = (os > bs) || (os == bs && oj < bj);
      bs = take ? os : bs; bj = take ? oj : bj; bl = take ? ol : bl;
    }
    if (lane == r) selj = bj;
    if (lane == bl){
      #pragma unroll
      for (int c = 0; c < 6; c++) if (c == cpos) cs[c] = NEGINF;
      cm = cs[0]; cpos = 0; cj = ci[0];
      #pragma unroll
      for (int c = 1; c < 6; c++){ bool g = cs[c] > cm; cm = g ? cs[c] : cm; cpos = g ? c : cpos; cj = g ? ci[c] : cj; }
    }
  }

  double myex = -__builtin_inf();
  {
    int jc = __shfl(selj, 0);
    const float* cr = corpus + (long)jc * E_ + lane*8;
    f32x4 a0 = *(const f32x4*)cr;
    f32x4 a1 = *(const f32x4*)(cr + 4);
    for (int r = 0; r < NSEL; r++){
      f32x4 b0 = a0, b1 = a1;
      if (r + 1 < NSEL){
        int jn = __shfl(selj, r + 1);
        const float* nr = corpus + (long)jn * E_ + lane*8;
        b0 = *(const f32x4*)nr;
        b1 = *(const f32x4*)(nr + 4);
      }
      double ds = 0.0, dn = 0.0;
      #pragma unroll
      for (int u = 0; u < 4; u++){ ds += (double)a0[u]*(double)q0[u]; dn += (double)a0[u]*(double)a0[u]; }
      #pragma unroll
      for (int u = 0; u < 4; u++){ ds += (double)a1[u]*(double)q1[u]; dn += (double)a1[u]*(double)a1[u]; }
      #pragma unroll
      for (int o = 32; o; o >>= 1){ ds += __shfl_xor(ds, o, 64); dn += __shfl_xor(dn, o, 64); }
      double ex = ds / (fmax(sqrt(dn), 1e-12) * qn);
      if (lane == r) myex = ex;
      a0 = b0; a1 = b1;
    }
  }

  for (int i = 0; i < KTOP; i++){
    double bs = myex; int bj = selj; int bl = lane;
    #pragma unroll
    for (int o = 32; o; o >>= 1){
      double os = __shfl_xor(bs, o, 64);
      int    oj = __shfl_xor(bj, o, 64);
      int    ol = __shfl_xor(bl, o, 64);
      bool take = (os > bs) || (os == bs && oj < bj);
      bs = take ? os : bs; bj = take ? oj : bj; bl = take ? ol : bl;
    }
    if (lane == bl){
      myex = -__builtin_inf();
      outScore[(long)row*KTOP + i] = (float)bs;
      outIdxF [(long)row*KTOP + i] = (float)bj;
      outIdxI [(long)row*KTOP + i] = bj;
    }
  }
}

// ---------------- gather retrieved corpus rows (un-normalized) -> bf16 -------
__global__ void k_gather_bf16(const float* __restrict__ corpus, const int* __restrict__ topidx,
                              unsigned short* __restrict__ out){
  int row = blockIdx.x, t = threadIdx.x;
  #pragma unroll
  for (int seg = 0; seg < KTOP; seg++){
    int j = topidx[row*KTOP + seg];
    const float* src = corpus + ((long)j << 9);
    unsigned short* dst = out + ((long)row << 13) + (seg << 9);
    int e = t * 2;
    f32x2 v = *(const f32x2*)(src + e);
    dst[e] = f2bf(v[0]); dst[e+1] = f2bf(v[1]);
  }
}

// ---------------- final gemv: outcome = z2 @ op_w3 + b3 ----------------
__global__ void k_gemv_out(const float* __restrict__ z2, const float* __restrict__ w3,
                           const float* __restrict__ b3, float* __restrict__ outc){
  int gw = (blockIdx.x * 256 + threadIdx.x) >> 6, lane = threadIdx.x & 63;
  if (gw >= B_) return;
  const float* r = z2 + (long)gw * 512;
  int e = lane * 8;
  f32x4 a1 = *(const f32x4*)(r + e),  a2 = *(const f32x4*)(r + e + 4);
  f32x4 b1 = *(const f32x4*)(w3 + e), b2 = *(const f32x4*)(w3 + e + 4);
  float s = a1[0]*b1[0]+a1[1]*b1[1]+a1[2]*b1[2]+a1[3]*b1[3]
          + a2[0]*b2[0]+a2[1]*b2[1]+a2[2]*b2[2]+a2[3]*b2[3];
  #pragma unroll
  for (int o = 32; o; o >>= 1) s += __shfl_xor(s, o, 64);
  if (lane == 0) outc[gw] = s + b3[0];
}

extern "C" void kernel_launch(void* const* d_in, const int* in_sizes, int n_in,
                              void* d_out, int out_size, void* d_ws, size_t ws_size,
                              hipStream_t stream)
{
  (void)in_sizes; (void)n_in; (void)out_size; (void)ws_size;
  const float* patient     = (const float*)d_in[0];
  const float* treatment   = (const float*)d_in[1];
  const float* confounders = (const float*)d_in[2];
  const float* corpus      = (const float*)d_in[3];
  const float* pe_w1 = (const float*)d_in[4];  const float* pe_b1 = (const float*)d_in[5];
  const float* pe_w2 = (const float*)d_in[6];  const float* pe_b2 = (const float*)d_in[7];
  const float* te_w  = (const float*)d_in[8];  const float* te_b  = (const float*)d_in[9];
  const float* ce_w  = (const float*)d_in[10]; const float* ce_b  = (const float*)d_in[11];
  const float* co_w1 = (const float*)d_in[12]; const float* co_b1 = (const float*)d_in[13];
  const float* co_w2 = (const float*)d_in[14]; const float* co_b2 = (const float*)d_in[15];
  const float* re_w  = (const float*)d_in[16]; const float* re_b  = (const float*)d_in[17];
  const float* op_w1 = (const float*)d_in[18]; const float* op_b1 = (const float*)d_in[19];
  const float* op_w2 = (const float*)d_in[20]; const float* op_b2 = (const float*)d_in[21];
  const float* op_w3 = (const float*)d_in[22]; const float* op_b3 = (const float*)d_in[23];

  float* out = (float*)d_out;
  float* out_outcome = out;
  float* out_scores  = out + 2048;
  float* out_idxf    = out + 2048 + 32768;
  float* out_contr   = out + 2048 + 32768 + 32768;

  char* ws = (char*)d_ws;
  const size_t MB = 1024*1024;
  unsigned short* cb    = (unsigned short*)(ws + 0);        // 97.7 MB (corpus bf16)
  unsigned short* retr  = (unsigned short*)(ws + 0);        // 32 MB (after sim)
  unsigned short* reT   = (unsigned short*)(ws + 34*MB);    // 16 MB
  unsigned short* op1T  = (unsigned short*)(ws + 51*MB);    // 6.3 MB
  unsigned short* op2T  = (unsigned short*)(ws + 58*MB);    // 1 MB
  float* t2     = (float*)(ws + 60*MB);                     // 8 MB (dead before re_out)
  float* re_out = (float*)(ws + 60*MB);                     // 8 MB
  unsigned short* z1 = (unsigned short*)(ws + 69*MB);       // 4 MB
  float* z2     = (float*)(ws + 74*MB);                     // 4 MB
  float* te_emb = (float*)(ws + 98*MB);                     // 8 MB persist
  float* ce_emb = (float*)(ws + 107*MB);                    // 8 MB persist
  float* t1     = (float*)(ws + 116*MB);                    // 8 MB (phase A)
  float* pe_emb = (float*)(ws + 125*MB);                    // 8 MB (phase A)
  unsigned short* qb = (unsigned short*)(ws + 116*MB);      // 2 MB (phase B, t1 dead)
  float* candS = (float*)(ws + 119*MB);                     // 3.1 MB
  int*   candI = (int*)(ws + 126*MB);                       // 3.1 MB
  int*   topidx= (int*)(ws + 133*MB);                       // 128 KB

  dim3 blk(256);
  // --- encoders (fp32, query-precision-critical), scalar-B wave-strip ---
  k_gemm_f32<1,true ><<<dim3(32,32), blk, 0, stream>>>(patient, 320, nullptr, 0, pe_w1, pe_b1, t1, 1024, 320);
  k_gemm_f32<1,false><<<dim3(32,32), blk, 0, stream>>>(t1, 1024, nullptr, 0, pe_w2, pe_b2, pe_emb, 1024, 1024);
  k_gemm_f32<1,false><<<dim3(32,32), blk, 0, stream>>>(treatment, 64, nullptr, 0, te_w, te_b, te_emb, 1024, 64);
  k_gemm_f32<1,false><<<dim3(32,32), blk, 0, stream>>>(confounders, 256, nullptr, 0, ce_w, ce_b, ce_emb, 1024, 256);
  k_gemm_f32<2,true ><<<dim3(32,32), blk, 0, stream>>>(pe_emb, 1024, ce_emb, 1024, co_w1, co_b1, t2, 1024, 2048);
  k_gemm_f32<1,false><<<dim3(32,16), blk, 0, stream>>>(t2, 1024, nullptr, 0, co_w2, co_b2, out_contr, 512, 1024);
  // --- fused normalize + bf16 convert ---
  k_norm_bf16<<<dim3(512),   blk, 0, stream>>>(out_contr, qb, 2048);
  k_norm_bf16<<<dim3(25000), blk, 0, stream>>>(corpus, cb, 100000);
  // --- similarity + top-k ---
  k_sim_topk<<<dim3(256), dim3(512), 0, stream>>>(qb, cb, candS, candI);
  k_finalize<<<dim3(512), blk, 0, stream>>>(candS, candI, out_contr, corpus, out_scores, out_idxf, topidx);
  // --- retrieval encoder + outcome head (bf16 MFMA) ---
  k_gather_bf16<<<dim3(2048), blk, 0, stream>>>(corpus, topidx, retr);
  k_transpose_bf16<<<dim3(256,32), blk, 0, stream>>>(re_w,  reT,  8192, 1024);
  k_transpose_bf16<<<dim3(96,32),  blk, 0, stream>>>(op_w1, op1T, 3072, 1024);
  k_transpose_bf16<<<dim3(32,16),  blk, 0, stream>>>(op_w2, op2T, 1024, 512);
  k_gemm_bf16<1,false,false,false><<<dim3(32,16), blk, 0, stream>>>(retr, 8192, nullptr, 0, nullptr, reT, re_b, re_out, 1024, 8192);
  k_gemm_bf16<3,true, true, true ><<<dim3(32,16), blk, 0, stream>>>(te_emb, 1024, ce_emb, 1024, re_out, op1T, op_b1, z1, 1024, 3072);
  k_gemm_bf16<1,false,true, false><<<dim3(32, 8), blk, 0, stream>>>(z1, 1024, nullptr, 0, nullptr, op2T, op_b2, z2, 512, 1024);
  k_gemv_out<<<dim3(512), blk, 0, stream>>>(z2, op_w3, op_b3, out_outcome);
}

// Round 13
// 905.623 us; speedup vs baseline: 1.4475x; 1.4475x over previous
//
#include <hip/hip_runtime.h>
#include <math.h>

#define DEV static __device__ __forceinline__

typedef __attribute__((ext_vector_type(4))) float f32x4;
typedef __attribute__((ext_vector_type(16))) float f32x16;
typedef __attribute__((ext_vector_type(2))) float f32x2;
typedef __attribute__((ext_vector_type(8))) short bf16x8;

#define B_    2048
#define N_    100000
#define E_    512
#define KTOP  16
#define CHUNK 3125
#define NCHUNK 32
#define KVR   32                       /* corpus rows per jt tile */
#define SLAB  528                      /* 33*16B granule stride */
#define TOPS  6                        /* top-6 per (chunk, lane-hi stripe) */
#define NCAND (NCHUNK*2*TOPS)          /* 384 per row */
#define NSEL  48
#define NEGINF (-__builtin_inff())

DEV unsigned short f2bf(float f){
  union { float f; unsigned u; } v; v.f = f;
  unsigned r = v.u + 0x7fffu + ((v.u >> 16) & 1u);
  return (unsigned short)(r >> 16);
}

DEV f32x16 mfma32(bf16x8 a, bf16x8 b, f32x16 c){
  return __builtin_amdgcn_mfma_f32_32x32x16_bf16(a, b, c, 0, 0, 0);
}
DEV f32x4 mfma16(bf16x8 a, bf16x8 b, f32x4 c){
  return __builtin_amdgcn_mfma_f32_16x16x32_bf16(a, b, c, 0, 0, 0);
}
DEV f32x16 zero16(){
  f32x16 z;
  #pragma unroll
  for (int i = 0; i < 16; i++) z[i] = 0.f;
  return z;
}

// swizzled LDS helpers for bf16 tiles (byte ^= (row&7)<<4)
DEV void lds_w8(unsigned short* base, int row, int k, int stride, bf16x8 v){
  char* p = (char*)base + (((row*stride + k)*2) ^ ((row & 7) << 4));
  *(bf16x8*)p = v;
}
DEV bf16x8 lds_r8(const unsigned short* base, int row, int k, int stride){
  const char* p = (const char*)base + (((row*stride + k)*2) ^ ((row & 7) << 4));
  return *(const bf16x8*)p;
}

// global -> LDS direct DMA, 16B per lane (proven in R2-R5 sim kernels).
DEV void gload_lds16(const void* g, void* l){
  __builtin_amdgcn_global_load_lds(
      (const __attribute__((address_space(1))) void*)(unsigned long long)(uintptr_t)g,
      (__attribute__((address_space(3))) void*)(unsigned)(uintptr_t)l,
      16, 0, 0);
}

// ---------------- fused row L2-normalize + bf16 convert (1 wave / row) -------
__global__ void k_norm_bf16(const float* __restrict__ x, unsigned short* __restrict__ out, int rows){
  int gw = (blockIdx.x * 256 + threadIdx.x) >> 6;
  int lane = threadIdx.x & 63;
  if (gw >= rows) return;
  const float* r = x + (long)gw * E_;
  f32x4 v0 = *(const f32x4*)(r + lane*8);
  f32x4 v1 = *(const f32x4*)(r + lane*8 + 4);
  float s = v0[0]*v0[0]+v0[1]*v0[1]+v0[2]*v0[2]+v0[3]*v0[3]
          + v1[0]*v1[0]+v1[1]*v1[1]+v1[2]*v1[2]+v1[3]*v1[3];
  #pragma unroll
  for (int o = 32; o; o >>= 1) s += __shfl_xor(s, o, 64);
  float inv = 1.f / fmaxf(sqrtf(s), 1e-12f);
  bf16x8 o;
  o[0]=(short)f2bf(v0[0]*inv); o[1]=(short)f2bf(v0[1]*inv); o[2]=(short)f2bf(v0[2]*inv); o[3]=(short)f2bf(v0[3]*inv);
  o[4]=(short)f2bf(v1[0]*inv); o[5]=(short)f2bf(v1[1]*inv); o[6]=(short)f2bf(v1[2]*inv); o[7]=(short)f2bf(v1[3]*inv);
  *(bf16x8*)(out + (long)gw*E_ + lane*8) = o;
}

// ---------------- fp32 GEMM (encoders): C = act(A @ W + b), W is [K,N] ------
// R8/R11-proven config: 64x64 tile, 256 threads, 4x4 acc, grid 512 = 2/CU.
// (R12 lesson: "wave-uniform B via scalar path" does NOT scalarize — compiler
// emits per-lane global_loads -> VMEM-bound, 370us/dispatch. R10 lesson: 8x8
// acc spills. This 2 B/FMA version sits at its ~52TF LDS ceiling; accepted.)
template<int NSEG, bool RELU>
__global__ __launch_bounds__(256) void k_gemm_f32(
    const float* __restrict__ A0, int K0,
    const float* __restrict__ A1, int K1,
    const float* __restrict__ Bw, const float* __restrict__ bias,
    float* __restrict__ C, int N, int Ktot)
{
  __shared__ float At[16][68];   // [k][m]
  __shared__ float Bt[16][68];   // [k][n]
  int bm = blockIdx.x * 64, bn = blockIdx.y * 64;
  int t = threadIdx.x;
  int tx = t & 15, ty = t >> 4;
  int ar = t >> 2, ac = (t & 3) * 4;
  float acc[4][4] = {};
  for (int k0 = 0; k0 < Ktot; k0 += 16){
    {
      int gk = k0 + ac;
      const float* src = A0; int kk = gk, ld = K0;
      if (NSEG == 2 && gk >= K0){ src = A1; kk = gk - K0; ld = K1; }
      f32x4 v = *(const f32x4*)(src + (long)(bm + ar) * ld + kk);
      #pragma unroll
      for (int i = 0; i < 4; i++) At[ac+i][ar] = v[i];
    }
    *(f32x4*)&Bt[ty][tx*4] = *(const f32x4*)(Bw + (long)(k0 + ty) * N + bn + tx*4);
    __syncthreads();
    #pragma unroll
    for (int k = 0; k < 16; k++){
      f32x4 a = *(const f32x4*)&At[k][ty*4];
      f32x4 b = *(const f32x4*)&Bt[k][tx*4];
      #pragma unroll
      for (int i = 0; i < 4; i++)
        #pragma unroll
        for (int j = 0; j < 4; j++) acc[i][j] += a[i]*b[j];
    }
    __syncthreads();
  }
  f32x4 bi = *(const f32x4*)(bias + bn + tx*4);
  #pragma unroll
  for (int i = 0; i < 4; i++){
    int m = bm + ty*4 + i;
    f32x4 v;
    #pragma unroll
    for (int j = 0; j < 4; j++){
      float x = acc[i][j] + bi[j];
      v[j] = RELU ? fmaxf(x, 0.f) : x;
    }
    *(f32x4*)(C + (long)m*N + bn + tx*4) = v;
  }
}

// ---------------- transpose fp32 [K,N] -> bf16 [N,K] ----------------
__global__ void k_transpose_bf16(const float* __restrict__ W, unsigned short* __restrict__ WT, int K, int N){
  __shared__ float tile[32][33];
  int k0 = blockIdx.x * 32, n0 = blockIdx.y * 32;
  int tx = threadIdx.x & 31, ty = threadIdx.x >> 5;
  #pragma unroll
  for (int r = 0; r < 32; r += 8) tile[ty + r][tx] = W[(long)(k0 + ty + r) * N + n0 + tx];
  __syncthreads();
  #pragma unroll
  for (int r = 0; r < 32; r += 8) WT[(long)(n0 + ty + r) * K + k0 + tx] = f2bf(tile[tx][ty + r]);
}

// ---------------- bf16 MFMA NT GEMM: C = act(A @ Bt^T + bias) ----------------
// Staging via global_load_lds (guide §5 ladder: width-16 DMA = the 517->874
// step; Common-mistake #1). Source byte is inverse-swizzled so LDS content is
// byte-identical to the old lds_w8 layout (XOR involution; read side
// unchanged). B always DMAs; A DMAs when already bf16 (AF32 keeps the
// register-convert path).
template<int NSEG, bool AF32, bool RELU, bool OUTBF16>
__global__ __launch_bounds__(256) void k_gemm_bf16(
    const void* __restrict__ A0p, int K0,
    const void* __restrict__ A1p, int K1,
    const void* __restrict__ A2p,
    const unsigned short* __restrict__ Bt, const float* __restrict__ bias,
    void* __restrict__ Cp, int N, int Ktot)
{
  __shared__ unsigned short Ash[64*64];
  __shared__ unsigned short Bsh[64*64];
  int bm = blockIdx.x * 64, bn = blockIdx.y * 64;
  int t = threadIdx.x, lane = t & 63, wid = t >> 6;
  int wr = wid >> 1, wc = wid & 1;
  int r16 = lane & 15, khalf = lane >> 4;
  int srow = t >> 2, skc = (t & 3) * 16;
  // DMA staging geometry: wave w covers rows {8w..8w+7} and {32+8w..} of the
  // 64-row tile; lane's 16B -> row rowbase+(lane>>3), byte (lane&7)*16.
  int dgr = lane >> 3;                       // row within 8-row group
  int dcol = ((lane & 7) ^ dgr) << 4;        // swizzled source byte within 128B row
  f32x4 acc00 = {0,0,0,0}, acc01 = {0,0,0,0}, acc10 = {0,0,0,0}, acc11 = {0,0,0,0};

  for (int k0 = 0; k0 < Ktot; k0 += 64){
    int gk = k0 + skc;
    if (!AF32){
      const char* A = (const char*)A0p;
      #pragma unroll
      for (int g = 0; g < 2; g++){
        int rowbase = g*32 + (wid << 3);
        const char* src = A + ((long)(bm + rowbase + dgr) * Ktot + k0) * 2 + dcol;
        gload_lds16(src, (char*)Ash + rowbase * 128);
      }
    } else {
      const float* s; int kk, ld;
      if (NSEG >= 2 && gk >= K0){
        if (NSEG == 3 && gk >= K0 + K1){ s = (const float*)A2p; kk = gk - K0 - K1; ld = Ktot - K0 - K1; }
        else                           { s = (const float*)A1p; kk = gk - K0;      ld = K1; }
      } else { s = (const float*)A0p; kk = gk; ld = K0; }
      const float* p = s + (long)(bm + srow) * ld + kk;
      f32x4 f0 = *(const f32x4*)p, f1 = *(const f32x4*)(p+4), f2 = *(const f32x4*)(p+8), f3 = *(const f32x4*)(p+12);
      bf16x8 v0, v1;
      v0[0]=(short)f2bf(f0[0]); v0[1]=(short)f2bf(f0[1]); v0[2]=(short)f2bf(f0[2]); v0[3]=(short)f2bf(f0[3]);
      v0[4]=(short)f2bf(f1[0]); v0[5]=(short)f2bf(f1[1]); v0[6]=(short)f2bf(f1[2]); v0[7]=(short)f2bf(f1[3]);
      v1[0]=(short)f2bf(f2[0]); v1[1]=(short)f2bf(f2[1]); v1[2]=(short)f2bf(f2[2]); v1[3]=(short)f2bf(f2[3]);
      v1[4]=(short)f2bf(f3[0]); v1[5]=(short)f2bf(f3[1]); v1[6]=(short)f2bf(f3[2]); v1[7]=(short)f2bf(f3[3]);
      lds_w8(Ash, srow, skc, 64, v0);
      lds_w8(Ash, srow, skc + 8, 64, v1);
    }
    {
      const char* Bc = (const char*)Bt;
      #pragma unroll
      for (int g = 0; g < 2; g++){
        int rowbase = g*32 + (wid << 3);
        const char* src = Bc + ((long)(bn + rowbase + dgr) * Ktot + k0) * 2 + dcol;
        gload_lds16(src, (char*)Bsh + rowbase * 128);
      }
    }
    __syncthreads();   // drains vmcnt (DMA) + lgkm before reads
    #pragma unroll
    for (int ks = 0; ks < 2; ks++){
      int kb = ks*32 + khalf*8;
      bf16x8 a0 = lds_r8(Ash, wr*32 +      r16, kb, 64);
      bf16x8 a1 = lds_r8(Ash, wr*32 + 16 + r16, kb, 64);
      bf16x8 b0 = lds_r8(Bsh, wc*32 +      r16, kb, 64);
      bf16x8 b1 = lds_r8(Bsh, wc*32 + 16 + r16, kb, 64);
      acc00 = mfma16(a0, b0, acc00);
      acc01 = mfma16(a0, b1, acc01);
      acc10 = mfma16(a1, b0, acc10);
      acc11 = mfma16(a1, b1, acc11);
    }
    __syncthreads();
  }
  #pragma unroll
  for (int r = 0; r < 4; r++){
    int mA = bm + wr*32 +      khalf*4 + r;
    int mB = bm + wr*32 + 16 + khalf*4 + r;
    int nA = bn + wc*32 +      r16;
    int nB = bn + wc*32 + 16 + r16;
    float v00 = acc00[r] + bias[nA]; float v01 = acc01[r] + bias[nB];
    float v10 = acc10[r] + bias[nA]; float v11 = acc11[r] + bias[nB];
    if (RELU){ v00 = fmaxf(v00,0.f); v01 = fmaxf(v01,0.f); v10 = fmaxf(v10,0.f); v11 = fmaxf(v11,0.f); }
    if (OUTBF16){
      unsigned short* C = (unsigned short*)Cp;
      C[(long)mA*N + nA] = f2bf(v00); C[(long)mA*N + nB] = f2bf(v01);
      C[(long)mB*N + nA] = f2bf(v10); C[(long)mB*N + nB] = f2bf(v11);
    } else {
      float* C = (float*)Cp;
      C[(long)mA*N + nA] = v00; C[(long)mA*N + nB] = v01;
      C[(long)mB*N + nA] = v10; C[(long)mB*N + nB] = v11;
    }
  }
}

// ---------------- similarity GEMM + fused in-register top-6 ------------------
// (unchanged from R11: 306us, SQ_LDS_BANK_CONFLICT = 0)
__global__ __launch_bounds__(512) __attribute__((amdgpu_waves_per_eu(2, 2)))
void k_sim_topk(
    const unsigned short* __restrict__ Qb, const unsigned short* __restrict__ Cb,
    float* __restrict__ candS, int* __restrict__ candI)
{
  __shared__ char Csh0[64*SLAB];   // 33 KB
  __shared__ char Csh1[64*SLAB];   // 33 KB
  int bid = blockIdx.x;
  int chunk = ((bid & 7) << 2) | (bid >> 6);
  int rowtile = (bid >> 3) & 7;
  int t = threadIdx.x, lane = t & 63, wid = t >> 6;   // wid 0..7
  int q32 = lane & 31, hi = lane >> 5;
  int jb0 = chunk * CHUNK;
  const int njt = (CHUNK + KVR - 1) / KVR;            // 98 (even)

  bf16x8 qreg[32];
  {
    const unsigned short* qb = Qb + ((long)(rowtile*256 + wid*32 + q32) << 9) + hi*8;
    #pragma unroll
    for (int ks = 0; ks < 32; ks++)
      qreg[ks] = *(const bf16x8*)(qb + ks*16);
  }
  #pragma unroll
  for (int ks = 0; ks < 32; ks++)
    asm volatile("" : "+v"(qreg[ks]));

  float ts[TOPS]; int ti[TOPS];
  #pragma unroll
  for (int q = 0; q < TOPS; q++){ ts[q] = NEGINF; ti[q] = 0; }
  float rmn = NEGINF;

  int lr = t >> 4;                                    // 0..31
  const char* gsrc = (const char*)Cb + (long)(jb0 + lr) * 1024 + (t & 15) * 16;
  unsigned wbase = (unsigned)((t & 15) * SLAB + lr * 16);
  unsigned rbase = (unsigned)(hi * SLAB + q32 * 16);

  auto dosel = [&](f32x16 a, int jb, int nv, bool tail){
    if (tail){
      #pragma unroll
      for (int r = 0; r < 16; r++){
        int crow = (r & 3) + 8*(r >> 2) + 4*hi;
        if (crow >= nv) a[r] = NEGINF;
      }
    }
    float m16 = a[0];
    #pragma unroll
    for (int r = 1; r < 16; r++) m16 = fmaxf(m16, a[r]);
    if (m16 > rmn){
      #pragma unroll
      for (int r = 0; r < 16; r++){
        float s = a[r];
        if (s > rmn){
          int j = jb + (r & 3) + 8*(r >> 2) + 4*hi;
          float mn = ts[0]; int ms = 0;
          #pragma unroll
          for (int q = 1; q < TOPS; q++){ bool lt = ts[q] < mn; mn = lt ? ts[q] : mn; ms = lt ? q : ms; }
          #pragma unroll
          for (int q = 0; q < TOPS; q++){ bool h = (ms == q); ts[q] = h ? s : ts[q]; ti[q] = h ? j : ti[q]; }
          float nm = ts[0];
          #pragma unroll
          for (int q = 1; q < TOPS; q++) nm = fminf(nm, ts[q]);
          rmn = nm;
        }
      }
    }
  };

  auto step = [&](int jt, const char* rbuf, char* wbuf){
    bool haveNext = (jt + 1 < njt);
    f32x4 n0, n1, n2, n3;
    if (haveNext){
      n0 = *(const f32x4*)(gsrc);
      n1 = *(const f32x4*)(gsrc + 256);
      n2 = *(const f32x4*)(gsrc + 512);
      n3 = *(const f32x4*)(gsrc + 768);
      gsrc += KVR * 1024;
    }
    f32x16 accA = zero16(), accB = zero16();
    const char* rp = rbuf + rbase;
    #pragma unroll
    for (int ks = 0; ks < 32; ks += 2){
      bf16x8 a0 = *(const bf16x8*)(rp + ks*(2*SLAB));
      bf16x8 a1 = *(const bf16x8*)(rp + (ks+1)*(2*SLAB));
      accA = mfma32(a0, qreg[ks],   accA);
      accB = mfma32(a1, qreg[ks+1], accB);
    }
    f32x16 acc = accA + accB;
    if (haveNext){
      char* wb = wbuf + wbase;
      *(f32x4*)(wb)            = n0;
      *(f32x4*)(wb + 16*SLAB)  = n1;
      *(f32x4*)(wb + 32*SLAB)  = n2;
      *(f32x4*)(wb + 48*SLAB)  = n3;
    }
    int jb = jb0 + jt*KVR;
    int nv = jb0 + CHUNK - jb;
    dosel(acc, jb, nv, nv < KVR);
    __syncthreads();
  };

  {
    f32x4 s0 = *(const f32x4*)(gsrc);
    f32x4 s1 = *(const f32x4*)(gsrc + 256);
    f32x4 s2 = *(const f32x4*)(gsrc + 512);
    f32x4 s3 = *(const f32x4*)(gsrc + 768);
    gsrc += KVR * 1024;
    char* wb = Csh0 + wbase;
    *(f32x4*)(wb)            = s0;
    *(f32x4*)(wb + 16*SLAB)  = s1;
    *(f32x4*)(wb + 32*SLAB)  = s2;
    *(f32x4*)(wb + 48*SLAB)  = s3;
    __syncthreads();
  }
  for (int jt = 0; jt < njt; jt += 2){
    step(jt,     Csh0, Csh1);
    step(jt + 1, Csh1, Csh0);
  }

  {
    int grow = rowtile*256 + wid*32 + q32;
    long o = (((long)grow * NCHUNK + chunk) * 2 + hi) * TOPS;
    #pragma unroll
    for (int q = 0; q < TOPS; q++){ candS[o+q] = ts[q]; candI[o+q] = ti[q]; }
  }
}

// ---------------- finalize: wave-per-row, register merge + fp64 rescore ------
__global__ __launch_bounds__(256) void k_finalize(
    const float* __restrict__ candS, const int* __restrict__ candI,
    const float* __restrict__ contrast, const float* __restrict__ corpus,
    float* __restrict__ outScore, float* __restrict__ outIdxF, int* __restrict__ outIdxI)
{
  int t = threadIdx.x, lane = t & 63, wid = t >> 6;
  int row = blockIdx.x * 4 + wid;

  float cs[6]; int ci[6];
  {
    const float* cp = candS + (long)row * NCAND + lane * 6;
    const int*   ip = candI + (long)row * NCAND + lane * 6;
    #pragma unroll
    for (int c = 0; c < 6; c++){ cs[c] = cp[c]; ci[c] = ip[c]; }
  }
  f32x4 q0 = *(const f32x4*)(contrast + (long)row*E_ + lane*8);
  f32x4 q1 = *(const f32x4*)(contrast + (long)row*E_ + lane*8 + 4);
  double qs = 0.0;
  #pragma unroll
  for (int u = 0; u < 4; u++){ qs += (double)q0[u]*(double)q0[u]; qs += (double)q1[u]*(double)q1[u]; }
  #pragma unroll
  for (int o = 32; o; o >>= 1) qs += __shfl_xor(qs, o, 64);
  double qn = fmax(sqrt(qs), 1e-12);

  float cm = cs[0]; int cpos = 0, cj = ci[0];
  #pragma unroll
  for (int c = 1; c < 6; c++){ bool g = cs[c] > cm; cm = g ? cs[c] : cm; cpos = g ? c : cpos; cj = g ? ci[c] : cj; }

  int selj = 0;
  for (int r = 0; r < NSEL; r++){
    float bs = cm; int bj = cj; int bl = lane;
    #pragma unroll
    for (int o = 32; o; o >>= 1){
      float os = __shfl_xor(bs, o, 64);
      int   oj = __shfl_xor(bj, o, 64);
      int   ol = __shfl_xor(bl, o, 64);
      bool take = (os > bs) || (os == bs && oj < bj);
      bs = take ? os : bs; bj = take ? oj : bj; bl = take ? ol : bl;
    }
    if (lane == r) selj = bj;
    if (lane == bl){
      #pragma unroll
      for (int c = 0; c < 6; c++) if (c == cpos) cs[c] = NEGINF;
      cm = cs[0]; cpos = 0; cj = ci[0];
      #pragma unroll
      for (int c = 1; c < 6; c++){ bool g = cs[c] > cm; cm = g ? cs[c] : cm; cpos = g ? c : cpos; cj = g ? ci[c] : cj; }
    }
  }

  double myex = -__builtin_inf();
  {
    int jc = __shfl(selj, 0);
    const float* cr = corpus + (long)jc * E_ + lane*8;
    f32x4 a0 = *(const f32x4*)cr;
    f32x4 a1 = *(const f32x4*)(cr + 4);
    for (int r = 0; r < NSEL; r++){
      f32x4 b0 = a0, b1 = a1;
      if (r + 1 < NSEL){
        int jn = __shfl(selj, r + 1);
        const float* nr = corpus + (long)jn * E_ + lane*8;
        b0 = *(const f32x4*)nr;
        b1 = *(const f32x4*)(nr + 4);
      }
      double ds = 0.0, dn = 0.0;
      #pragma unroll
      for (int u = 0; u < 4; u++){ ds += (double)a0[u]*(double)q0[u]; dn += (double)a0[u]*(double)a0[u]; }
      #pragma unroll
      for (int u = 0; u < 4; u++){ ds += (double)a1[u]*(double)q1[u]; dn += (double)a1[u]*(double)a1[u]; }
      #pragma unroll
      for (int o = 32; o; o >>= 1){ ds += __shfl_xor(ds, o, 64); dn += __shfl_xor(dn, o, 64); }
      double ex = ds / (fmax(sqrt(dn), 1e-12) * qn);
      if (lane == r) myex = ex;
      a0 = b0; a1 = b1;
    }
  }

  for (int i = 0; i < KTOP; i++){
    double bs = myex; int bj = selj; int bl = lane;
    #pragma unroll
    for (int o = 32; o; o >>= 1){
      double os = __shfl_xor(bs, o, 64);
      int    oj = __shfl_xor(bj, o, 64);
      int    ol = __shfl_xor(bl, o, 64);
      bool take = (os > bs) || (os == bs && oj < bj);
      bs = take ? os : bs; bj = take ? oj : bj; bl = take ? ol : bl;
    }
    if (lane == bl){
      myex = -__builtin_inf();
      outScore[(long)row*KTOP + i] = (float)bs;
      outIdxF [(long)row*KTOP + i] = (float)bj;
      outIdxI [(long)row*KTOP + i] = bj;
    }
  }
}

// ---------------- gather retrieved corpus rows (un-normalized) -> bf16 -------
__global__ void k_gather_bf16(const float* __restrict__ corpus, const int* __restrict__ topidx,
                              unsigned short* __restrict__ out){
  int row = blockIdx.x, t = threadIdx.x;
  #pragma unroll
  for (int seg = 0; seg < KTOP; seg++){
    int j = topidx[row*KTOP + seg];
    const float* src = corpus + ((long)j << 9);
    unsigned short* dst = out + ((long)row << 13) + (seg << 9);
    int e = t * 2;
    f32x2 v = *(const f32x2*)(src + e);
    dst[e] = f2bf(v[0]); dst[e+1] = f2bf(v[1]);
  }
}

// ---------------- final gemv: outcome = z2 @ op_w3 + b3 ----------------
__global__ void k_gemv_out(const float* __restrict__ z2, const float* __restrict__ w3,
                           const float* __restrict__ b3, float* __restrict__ outc){
  int gw = (blockIdx.x * 256 + threadIdx.x) >> 6, lane = threadIdx.x & 63;
  if (gw >= B_) return;
  const float* r = z2 + (long)gw * 512;
  int e = lane * 8;
  f32x4 a1 = *(const f32x4*)(r + e),  a2 = *(const f32x4*)(r + e + 4);
  f32x4 b1 = *(const f32x4*)(w3 + e), b2 = *(const f32x4*)(w3 + e + 4);
  float s = a1[0]*b1[0]+a1[1]*b1[1]+a1[2]*b1[2]+a1[3]*b1[3]
          + a2[0]*b2[0]+a2[1]*b2[1]+a2[2]*b2[2]+a2[3]*b2[3];
  #pragma unroll
  for (int o = 32; o; o >>= 1) s += __shfl_xor(s, o, 64);
  if (lane == 0) outc[gw] = s + b3[0];
}

extern "C" void kernel_launch(void* const* d_in, const int* in_sizes, int n_in,
                              void* d_out, int out_size, void* d_ws, size_t ws_size,
                              hipStream_t stream)
{
  (void)in_sizes; (void)n_in; (void)out_size; (void)ws_size;
  const float* patient     = (const float*)d_in[0];
  const float* treatment   = (const float*)d_in[1];
  const float* confounders = (const float*)d_in[2];
  const float* corpus      = (const float*)d_in[3];
  const float* pe_w1 = (const float*)d_in[4];  const float* pe_b1 = (const float*)d_in[5];
  const float* pe_w2 = (const float*)d_in[6];  const float* pe_b2 = (const float*)d_in[7];
  const float* te_w  = (const float*)d_in[8];  const float* te_b  = (const float*)d_in[9];
  const float* ce_w  = (const float*)d_in[10]; const float* ce_b  = (const float*)d_in[11];
  const float* co_w1 = (const float*)d_in[12]; const float* co_b1 = (const float*)d_in[13];
  const float* co_w2 = (const float*)d_in[14]; const float* co_b2 = (const float*)d_in[15];
  const float* re_w  = (const float*)d_in[16]; const float* re_b  = (const float*)d_in[17];
  const float* op_w1 = (const float*)d_in[18]; const float* op_b1 = (const float*)d_in[19];
  const float* op_w2 = (const float*)d_in[20]; const float* op_b2 = (const float*)d_in[21];
  const float* op_w3 = (const float*)d_in[22]; const float* op_b3 = (const float*)d_in[23];

  float* out = (float*)d_out;
  float* out_outcome = out;
  float* out_scores  = out + 2048;
  float* out_idxf    = out + 2048 + 32768;
  float* out_contr   = out + 2048 + 32768 + 32768;

  char* ws = (char*)d_ws;
  const size_t MB = 1024*1024;
  unsigned short* cb    = (unsigned short*)(ws + 0);        // 97.7 MB (corpus bf16)
  unsigned short* retr  = (unsigned short*)(ws + 0);        // 32 MB (after sim)
  unsigned short* reT   = (unsigned short*)(ws + 34*MB);    // 16 MB
  unsigned short* op1T  = (unsigned short*)(ws + 51*MB);    // 6.3 MB
  unsigned short* op2T  = (unsigned short*)(ws + 58*MB);    // 1 MB
  float* t2     = (float*)(ws + 60*MB);                     // 8 MB (dead before re_out)
  float* re_out = (float*)(ws + 60*MB);                     // 8 MB
  unsigned short* z1 = (unsigned short*)(ws + 69*MB);       // 4 MB
  float* z2     = (float*)(ws + 74*MB);                     // 4 MB
  float* te_emb = (float*)(ws + 98*MB);                     // 8 MB persist
  float* ce_emb = (float*)(ws + 107*MB);                    // 8 MB persist
  float* t1     = (float*)(ws + 116*MB);                    // 8 MB (phase A)
  float* pe_emb = (float*)(ws + 125*MB);                    // 8 MB (phase A)
  unsigned short* qb = (unsigned short*)(ws + 116*MB);      // 2 MB (phase B, t1 dead)
  float* candS = (float*)(ws + 119*MB);                     // 3.1 MB
  int*   candI = (int*)(ws + 126*MB);                       // 3.1 MB
  int*   topidx= (int*)(ws + 133*MB);                       // 128 KB

  dim3 blk(256);
  // --- encoders (fp32, query-precision-critical), 64x64 tiles (R8/R11) ---
  k_gemm_f32<1,true ><<<dim3(32,16), blk, 0, stream>>>(patient, 320, nullptr, 0, pe_w1, pe_b1, t1, 1024, 320);
  k_gemm_f32<1,false><<<dim3(32,16), blk, 0, stream>>>(t1, 1024, nullptr, 0, pe_w2, pe_b2, pe_emb, 1024, 1024);
  k_gemm_f32<1,false><<<dim3(32,16), blk, 0, stream>>>(treatment, 64, nullptr, 0, te_w, te_b, te_emb, 1024, 64);
  k_gemm_f32<1,false><<<dim3(32,16), blk, 0, stream>>>(confounders, 256, nullptr, 0, ce_w, ce_b, ce_emb, 1024, 256);
  k_gemm_f32<2,true ><<<dim3(32,16), blk, 0, stream>>>(pe_emb, 1024, ce_emb, 1024, co_w1, co_b1, t2, 1024, 2048);
  k_gemm_f32<1,false><<<dim3(32, 8), blk, 0, stream>>>(t2, 1024, nullptr, 0, co_w2, co_b2, out_contr, 512, 1024);
  // --- fused normalize + bf16 convert ---
  k_norm_bf16<<<dim3(512),   blk, 0, stream>>>(out_contr, qb, 2048);
  k_norm_bf16<<<dim3(25000), blk, 0, stream>>>(corpus, cb, 100000);
  // --- similarity + top-k ---
  k_sim_topk<<<dim3(256), dim3(512), 0, stream>>>(qb, cb, candS, candI);
  k_finalize<<<dim3(512), blk, 0, stream>>>(candS, candI, out_contr, corpus, out_scores, out_idxf, topidx);
  // --- retrieval encoder + outcome head (bf16 MFMA, DMA-staged) ---
  k_gather_bf16<<<dim3(2048), blk, 0, stream>>>(corpus, topidx, retr);
  k_transpose_bf16<<<dim3(256,32), blk, 0, stream>>>(re_w,  reT,  8192, 1024);
  k_transpose_bf16<<<dim3(96,32),  blk, 0, stream>>>(op_w1, op1T, 3072, 1024);
  k_transpose_bf16<<<dim3(32,16),  blk, 0, stream>>>(op_w2, op2T, 1024, 512);
  k_gemm_bf16<1,false,false,false><<<dim3(32,16), blk, 0, stream>>>(retr, 8192, nullptr, 0, nullptr, reT, re_b, re_out, 1024, 8192);
  k_gemm_bf16<3,true, true, true ><<<dim3(32,16), blk, 0, stream>>>(te_emb, 1024, ce_emb, 1024, re_out, op1T, op_b1, z1, 1024, 3072);
  k_gemm_bf16<1,false,true, false><<<dim3(32, 8), blk, 0, stream>>>(z1, 1024, nullptr, 0, nullptr, op2T, op_b2, z2, 512, 1024);
  k_gemv_out<<<dim3(512), blk, 0, stream>>>(z2, op_w3, op_b3, out_outcome);
}